// Round 7
// baseline (251.496 us; speedup 1.0000x reference)
//
#include <hip/hip_runtime.h>
#include <math.h>

typedef _Float16 half_t;
typedef __attribute__((ext_vector_type(8))) _Float16 half8;
typedef __attribute__((ext_vector_type(4))) _Float16 half4;
typedef __attribute__((ext_vector_type(2))) _Float16 half2v;
typedef __attribute__((ext_vector_type(4))) float floatx4;

#define BATCH   8
#define SEQ     4096
#define DM      512
#define NP      256
#define M_TOT   32768
#define NTOT    768
#define CHUNKS  256
#define CHUNK_LEN 16

__device__ __forceinline__ void async_load16(const void* g, void* l) {
    __builtin_amdgcn_global_load_lds((const __attribute__((address_space(1))) void*)g,
                                     (__attribute__((address_space(3))) void*)l,
                                     16, 0, 0);
}

// ---------------------------------------------------------------------------
// decay + x fp32->fp16 convert (blocks 0..4095), fused with Wcat transpose
// (blocks 4096..4101) to save one launch.
// ---------------------------------------------------------------------------
__global__ __launch_bounds__(256) void decay_convert(const float* __restrict__ X,
                                                     const float* __restrict__ Wd,
                                                     const float* __restrict__ bd,
                                                     float* __restrict__ dec,
                                                     half_t* __restrict__ Xh,
                                                     const float* __restrict__ Wi,
                                                     const float* __restrict__ Wa,
                                                     half_t* __restrict__ Wt) {
    if (blockIdx.x >= M_TOT / 8) {
        // ---- Wcat_t[768][512] fp16 = [Wi^T ; Wa^T] ----
        const int idx = (blockIdx.x - M_TOT / 8) * 65536 + threadIdx.x * 256;
        // 6 blocks x 256 threads x 256 elems = 393216 = 768*512
        for (int e = 0; e < 256; ++e) {
            const int i = idx + e;
            const int n = i >> 9;
            const int k = i & 511;
            float v = (n < DM) ? Wi[(size_t)k * DM + n] : Wa[(size_t)k * NP + (n - DM)];
            Wt[i] = (half_t)v;
        }
        return;
    }
    const int wave = threadIdx.x >> 6;
    const int lane = threadIdx.x & 63;
    const int row0 = blockIdx.x * 8 + wave * 2;
    const float4* x0 = (const float4*)(X + (size_t)row0 * DM);
    const float4* x1 = x0 + 128;
    const float4* wd = (const float4*)Wd;
    float4 a0 = x0[2 * lane], a1 = x0[2 * lane + 1];
    float4 b0 = x1[2 * lane], b1 = x1[2 * lane + 1];
    float4 w0 = wd[2 * lane], w1 = wd[2 * lane + 1];
    float s0 = a0.x * w0.x + a0.y * w0.y + a0.z * w0.z + a0.w * w0.w
             + a1.x * w1.x + a1.y * w1.y + a1.z * w1.z + a1.w * w1.w;
    float s1 = b0.x * w0.x + b0.y * w0.y + b0.z * w0.z + b0.w * w0.w
             + b1.x * w1.x + b1.y * w1.y + b1.z * w1.z + b1.w * w1.w;
    half8 h0 = {(half_t)a0.x, (half_t)a0.y, (half_t)a0.z, (half_t)a0.w,
                (half_t)a1.x, (half_t)a1.y, (half_t)a1.z, (half_t)a1.w};
    half8 h1 = {(half_t)b0.x, (half_t)b0.y, (half_t)b0.z, (half_t)b0.w,
                (half_t)b1.x, (half_t)b1.y, (half_t)b1.z, (half_t)b1.w};
    *(half8*)(Xh + (size_t)row0 * DM + lane * 8) = h0;
    *(half8*)(Xh + (size_t)(row0 + 1) * DM + lane * 8) = h1;
#pragma unroll
    for (int off = 32; off > 0; off >>= 1) {
        s0 += __shfl_down(s0, off, 64);
        s1 += __shfl_down(s1, off, 64);
    }
    if (lane == 0) {
        dec[row0]     = 1.0f / (1.0f + __expf(-(s0 + bd[0])));
        dec[row0 + 1] = 1.0f / (1.0f + __expf(-(s1 + bd[0])));
    }
}

// ---------------------------------------------------------------------------
// Fused MFMA GEMM — proven single-buffer K-loop. Round-6 change: epilogue
// stages the fp16 C-tile through LDS (reusing As, two 64-row passes) so
// global stores are 16B/lane full-line half8 rows instead of 2B scalar
// quad-strided stores. Fixes the RMW over-fetch seen in r4 (FETCH 36->52MB).
// ---------------------------------------------------------------------------
__global__ __launch_bounds__(256) void gemm_fused(const half_t* __restrict__ Xh,
                                                  const half_t* __restrict__ Wt,
                                                  const float* __restrict__ bi,
                                                  const float* __restrict__ ba,
                                                  half_t* __restrict__ inj,
                                                  half_t* __restrict__ angles) {
    __shared__ __align__(16) char As[8192];
    __shared__ __align__(16) char Bs[8192];

    const int bm   = blockIdx.x;
    const int bn   = blockIdx.y;
    const int tid  = threadIdx.x;
    const int wave = tid >> 6;
    const int lane = tid & 63;
    const int quad = lane >> 4;
    const int l16  = lane & 15;
    const int wrow = wave >> 1;
    const int wcol = wave & 1;

    floatx4 acc[4][4];
#pragma unroll
    for (int i = 0; i < 4; ++i)
#pragma unroll
        for (int j = 0; j < 4; ++j) acc[i][j] = (floatx4){0.f, 0.f, 0.f, 0.f};

    const int s0 = wave * 128 + lane;
    const int s1 = s0 + 64;
    const int r0 = s0 >> 2, kql0 = (s0 & 3) ^ ((r0 >> 1) & 3);
    const int r1 = s1 >> 2, kql1 = (s1 & 3) ^ ((r1 >> 1) & 3);
    const half_t* gA0 = Xh + (size_t)(bm * 128 + r0) * DM + kql0 * 8;
    const half_t* gA1 = Xh + (size_t)(bm * 128 + r1) * DM + kql1 * 8;
    const half_t* gB0 = Wt + (size_t)(bn * 128 + r0) * DM + kql0 * 8;
    const half_t* gB1 = Wt + (size_t)(bn * 128 + r1) * DM + kql1 * 8;
    char* lA0 = As + wave * 2048;
    char* lA1 = As + wave * 2048 + 1024;
    char* lB0 = Bs + wave * 2048;
    char* lB1 = Bs + wave * 2048 + 1024;

    for (int k0 = 0; k0 < DM; k0 += 32) {
        async_load16(gA0 + k0, lA0);
        async_load16(gA1 + k0, lA1);
        async_load16(gB0 + k0, lB0);
        async_load16(gB1 + k0, lB1);
        __syncthreads();

        half8 af[4], bf[4];
#pragma unroll
        for (int mt = 0; mt < 4; ++mt) {
            const int r = wrow * 64 + mt * 16 + l16;
            af[mt] = *(const half8*)(As + r * 64 + ((quad ^ ((r >> 1) & 3)) << 4));
        }
#pragma unroll
        for (int nt = 0; nt < 4; ++nt) {
            const int r = wcol * 64 + nt * 16 + l16;
            bf[nt] = *(const half8*)(Bs + r * 64 + ((quad ^ ((r >> 1) & 3)) << 4));
        }
#pragma unroll
        for (int mt = 0; mt < 4; ++mt)
#pragma unroll
            for (int nt = 0; nt < 4; ++nt)
                acc[mt][nt] = __builtin_amdgcn_mfma_f32_16x16x32_f16(af[mt], bf[nt],
                                                                     acc[mt][nt], 0, 0, 0);
        __syncthreads();
    }

    // ---- epilogue: LDS-staged coalesced fp16 stores ----
    // Per bn-block the destination is uniform: bn<4 -> inj, bn>=4 -> angles.
    const bool  is_inj = (bn < 4);
    half_t*     dst    = is_inj ? inj    : angles;
    const int   ldd    = is_inj ? DM     : NP;
    const int   cb     = is_inj ? bn * 128 : bn * 128 - DM;

    // per-thread bias for its 4 nt columns (tile col = wcol*64 + nt*16 + l16)
    float bias[4];
#pragma unroll
    for (int nt = 0; nt < 4; ++nt) {
        const int colt = wcol * 64 + nt * 16 + l16;
        bias[nt] = is_inj ? bi[bn * 128 + colt] : ba[bn * 128 + colt - DM];
    }

    half_t* Cs = (half_t*)As;   // 16 KB = 64 rows x 128 cols fp16
#pragma unroll
    for (int rh = 0; rh < 2; ++rh) {
        __syncthreads();
        if (wrow == rh) {
#pragma unroll
            for (int mt = 0; mt < 4; ++mt)
#pragma unroll
                for (int nt = 0; nt < 4; ++nt)
#pragma unroll
                    for (int r = 0; r < 4; ++r) {
                        const int lr = mt * 16 + quad * 4 + r;
                        const int lc = wcol * 64 + nt * 16 + l16;
                        Cs[lr * 128 + lc] = (half_t)(acc[mt][nt][r] + bias[nt]);
                    }
        }
        __syncthreads();
        // 256 threads write 64 rows x 128 cols as half8 (16 units/row)
#pragma unroll
        for (int it = 0; it < 4; ++it) {
            const int idx = it * 256 + tid;      // 0..1023
            const int rr  = idx >> 4;            // 0..63
            const int cc  = (idx & 15) * 8;      // 0..120
            const int grow = bm * 128 + rh * 64 + rr;
            half8 v = *(half8*)(Cs + rr * 128 + cc);
            *(half8*)(dst + (size_t)grow * ldd + cb + cc) = v;
        }
    }
}

// ---------------------------------------------------------------------------
// sum1: per-chunk summaries. CHUNK_LEN=16 -> 1024 blocks.
// ---------------------------------------------------------------------------
__global__ __launch_bounds__(256) void scan_sum1(const half_t* __restrict__ angles,
                                                 const float* __restrict__ decays,
                                                 const half_t* __restrict__ inj,
                                                 float* __restrict__ thetaC,
                                                 float4* __restrict__ hend,
                                                 float* __restrict__ Dprod) {
    const int b   = blockIdx.x >> 7;
    const int sub = threadIdx.x >> 7;
    const int th  = threadIdx.x & 127;
    const int c   = (blockIdx.x & 127) * 2 + sub;
    const int p0  = th * 2;
    const int t0  = c * CHUNK_LEN;

    const half_t* ap = angles + (size_t)(b * SEQ + t0) * NP + p0;
    const half4*  up = (const half4*)(inj + (size_t)(b * SEQ + t0) * DM) + th;
    const float*  dp = decays + b * SEQ + t0;

    half2v ab[2][8]; half4 ub[2][8]; float db[2][8];
#pragma unroll
    for (int j = 0; j < 8; ++j) {
        ab[0][j] = *(const half2v*)(ap + (size_t)j * NP);
        ub[0][j] = up[(size_t)j * 128];
        db[0][j] = dp[j];
    }

    float h0a = 0, h1a = 0, h0b = 0, h1b = 0, tha = 0, thb = 0, dc = 1.0f;
#pragma unroll
    for (int g = 0; g < 2; ++g) {
        const int cur = g & 1, nxt = cur ^ 1;
        if (g < 1) {
#pragma unroll
            for (int j = 0; j < 8; ++j) {
                const int t = (g + 1) * 8 + j;
                ab[nxt][j] = *(const half2v*)(ap + (size_t)t * NP);
                ub[nxt][j] = up[(size_t)t * 128];
                db[nxt][j] = dp[t];
            }
        }
#pragma unroll
        for (int j = 0; j < 8; ++j) {
            float a0 = (float)ab[cur][j][0], a1 = (float)ab[cur][j][1];
            half4 uh = ub[cur][j];
            float d  = db[cur][j];
            float s0, c0, s1, c1;
            __sincosf(a0, &s0, &c0);
            __sincosf(a1, &s1, &c1);
            float n0a = fmaf(d, c0 * h0a - s0 * h1a, (float)uh[0]);
            float n1a = fmaf(d, s0 * h0a + c0 * h1a, (float)uh[1]);
            float n0b = fmaf(d, c1 * h0b - s1 * h1b, (float)uh[2]);
            float n1b = fmaf(d, s1 * h0b + c1 * h1b, (float)uh[3]);
            h0a = n0a; h1a = n1a; h0b = n0b; h1b = n1b;
            tha += a0; thb += a1; dc *= d;
        }
    }
    const size_t cbase = (size_t)(b * CHUNKS + c) * NP + p0;
    *(float2*)(thetaC + cbase) = make_float2(tha, thb);
    hend[cbase >> 1] = make_float4(h0a, h1a, h0b, h1b);
    if (th == 0) Dprod[b * CHUNKS + c] = dc;
}

// ---------------------------------------------------------------------------
// chunk-operator scan — Kogge-Stone in LDS. One block per (b, p-pair).
// ---------------------------------------------------------------------------
__global__ __launch_bounds__(256) void scan_chunks(const float* __restrict__ thetaC,
                                                   const float4* __restrict__ hend,
                                                   const float* __restrict__ Dprod,
                                                   float4* __restrict__ hentry) {
    const int b  = blockIdx.x >> 7;
    const int pp = blockIdx.x & 127;
    const int c  = threadIdx.x;

    __shared__ float  sTa[256], sTb[256], sD[256];
    __shared__ float4 sV[256];

    const size_t idx = (size_t)(b * CHUNKS + c);
    const float2 th2 = *(const float2*)(thetaC + idx * NP + pp * 2);
    float4 v = hend[idx * 128 + pp];
    float  D = Dprod[idx];
    float tha = th2.x, thb = th2.y;

    sTa[c] = tha; sTb[c] = thb; sD[c] = D; sV[c] = v;

#pragma unroll
    for (int o = 1; o < 256; o <<= 1) {
        __syncthreads();
        float lta = 0.f, ltb = 0.f, lD = 0.f;
        float4 lv = make_float4(0.f, 0.f, 0.f, 0.f);
        const bool has = (c >= o);
        if (has) { lta = sTa[c - o]; ltb = sTb[c - o]; lD = sD[c - o]; lv = sV[c - o]; }
        __syncthreads();
        if (has) {
            float s0, c0, s1, c1;
            __sincosf(tha, &s0, &c0);
            __sincosf(thb, &s1, &c1);
            v.x = fmaf(D, c0 * lv.x - s0 * lv.y, v.x);
            v.y = fmaf(D, s0 * lv.x + c0 * lv.y, v.y);
            v.z = fmaf(D, c1 * lv.z - s1 * lv.w, v.z);
            v.w = fmaf(D, s1 * lv.z + c1 * lv.w, v.w);
            tha += lta; thb += ltb; D *= lD;
            sTa[c] = tha; sTb[c] = thb; sD[c] = D; sV[c] = v;
        }
    }
    __syncthreads();
    const float4 e = (c == 0) ? make_float4(0.f, 0.f, 0.f, 0.f) : sV[c - 1];
    hentry[idx * 128 + pp] = e;
}

// ---------------------------------------------------------------------------
// final: redo local scan seeded with entry state; inj fp16; write out fp32.
// ---------------------------------------------------------------------------
__global__ __launch_bounds__(256) void scan_final(const half_t* __restrict__ angles,
                                                  const float* __restrict__ decays,
                                                  const half_t* __restrict__ inj,
                                                  const float4* __restrict__ hentry,
                                                  float* __restrict__ out) {
    const int b   = blockIdx.x >> 7;
    const int sub = threadIdx.x >> 7;
    const int th  = threadIdx.x & 127;
    const int c   = (blockIdx.x & 127) * 2 + sub;
    const int p0  = th * 2;
    const int t0  = c * CHUNK_LEN;

    const half_t* ap = angles + (size_t)(b * SEQ + t0) * NP + p0;
    const half4*  up = (const half4*)(inj + (size_t)(b * SEQ + t0) * DM) + th;
    float4*       op = (float4*)out + (size_t)(b * SEQ + t0) * 128 + (p0 >> 1);
    const float*  dp = decays + b * SEQ + t0;

    float4 v = hentry[(size_t)(b * CHUNKS + c) * 128 + (p0 >> 1)];
    float h0a = v.x, h1a = v.y, h0b = v.z, h1b = v.w;

    half2v ab[2][8]; half4 ub[2][8]; float db[2][8];
#pragma unroll
    for (int j = 0; j < 8; ++j) {
        ab[0][j] = *(const half2v*)(ap + (size_t)j * NP);
        ub[0][j] = up[(size_t)j * 128];
        db[0][j] = dp[j];
    }

#pragma unroll
    for (int g = 0; g < 2; ++g) {
        const int cur = g & 1, nxt = cur ^ 1;
        if (g < 1) {
#pragma unroll
            for (int j = 0; j < 8; ++j) {
                const int t = (g + 1) * 8 + j;
                ab[nxt][j] = *(const half2v*)(ap + (size_t)t * NP);
                ub[nxt][j] = up[(size_t)t * 128];
                db[nxt][j] = dp[t];
            }
        }
#pragma unroll
        for (int j = 0; j < 8; ++j) {
            const int t = g * 8 + j;
            float a0 = (float)ab[cur][j][0], a1 = (float)ab[cur][j][1];
            half4 uh = ub[cur][j];
            float d  = db[cur][j];
            float s0, c0, s1, c1;
            __sincosf(a0, &s0, &c0);
            __sincosf(a1, &s1, &c1);
            float n0a = fmaf(d, c0 * h0a - s0 * h1a, (float)uh[0]);
            float n1a = fmaf(d, s0 * h0a + c0 * h1a, (float)uh[1]);
            float n0b = fmaf(d, c1 * h0b - s1 * h1b, (float)uh[2]);
            float n1b = fmaf(d, s1 * h0b + c1 * h1b, (float)uh[3]);
            h0a = n0a; h1a = n1a; h0b = n0b; h1b = n1b;
            op[(size_t)t * 128] = make_float4(h0a, h1a, h0b, h1b);
        }
    }
}

// ---------------------------------------------------------------------------
extern "C" void kernel_launch(void* const* d_in, const int* in_sizes, int n_in,
                              void* d_out, int out_size, void* d_ws, size_t ws_size,
                              hipStream_t stream) {
    const float* x  = (const float*)d_in[0];
    const float* Wa = (const float*)d_in[1];
    const float* ba = (const float*)d_in[2];
    const float* Wd = (const float*)d_in[3];
    const float* bd = (const float*)d_in[4];
    const float* Wi = (const float*)d_in[5];
    const float* bi = (const float*)d_in[6];
    float* out = (float*)d_out;

    char* ws = (char*)d_ws;
    half_t* x_h     = (half_t*)(ws);                  // 33,554,432 B @ 0 (dead after gemm)
    float*  thetaC  = (float*)(ws);                   //  2,097,152 B (overlay, post-gemm)
    float4* hend    = (float4*)(ws + 2097152);        //  4,194,304 B (overlay)
    float*  Dprod   = (float*)(ws + 6291456);         //      8,192 B (overlay)
    float4* hentry  = (float4*)(ws + 6299648);        //  4,194,304 B (overlay)
    half_t* inj_h   = (half_t*)(ws + 33554432);       // 33,554,432 B
    half_t* angles  = (half_t*)(ws + 67108864);       // 16,777,216 B
    float*  decays  = (float*)(ws + 83886080);        //    131,072 B
    half_t* Wcat_t  = (half_t*)(ws + 84017152);       //    786,432 B  (ends 84,803,584)

    decay_convert<<<M_TOT / 8 + 6, 256, 0, stream>>>(x, Wd, bd, decays, x_h, Wi, Wa, Wcat_t);
    gemm_fused<<<dim3(M_TOT / 128, NTOT / 128), 256, 0, stream>>>(x_h, Wcat_t, bi, ba, inj_h, angles);

    scan_sum1<<<BATCH * CHUNKS / 2, 256, 0, stream>>>(angles, decays, inj_h, thetaC, hend, Dprod);
    scan_chunks<<<BATCH * 128, 256, 0, stream>>>(thetaC, hend, Dprod, hentry);
    scan_final<<<BATCH * CHUNKS / 2, 256, 0, stream>>>(angles, decays, inj_h, hentry, out);
}

// Round 8
// 203.296 us; speedup vs baseline: 1.2371x; 1.2371x over previous
//
#include <hip/hip_runtime.h>
#include <math.h>

typedef _Float16 half_t;
typedef __attribute__((ext_vector_type(8))) _Float16 half8;
typedef __attribute__((ext_vector_type(4))) _Float16 half4;
typedef __attribute__((ext_vector_type(2))) _Float16 half2v;
typedef __attribute__((ext_vector_type(4))) float floatx4;

#define BATCH   8
#define SEQ     4096
#define DM      512
#define NP      256
#define M_TOT   32768
#define NTOT    768
#define CHUNKS  256
#define CHUNK_LEN 16

__device__ __forceinline__ void async_load16(const void* g, void* l) {
    __builtin_amdgcn_global_load_lds((const __attribute__((address_space(1))) void*)g,
                                     (__attribute__((address_space(3))) void*)l,
                                     16, 0, 0);
}

// ---------------------------------------------------------------------------
// decay + x fp32->fp16 convert. 2 rows per wave (64B/lane in flight).
// (r7's fused wcat tail reverted: 6 serial tail-blocks stretched this kernel
//  to 81 us while 250 CUs idled. Launch fusion must never add a serial tail.)
// ---------------------------------------------------------------------------
__global__ __launch_bounds__(256) void decay_convert(const float* __restrict__ X,
                                                     const float* __restrict__ Wd,
                                                     const float* __restrict__ bd,
                                                     float* __restrict__ dec,
                                                     half_t* __restrict__ Xh) {
    const int wave = threadIdx.x >> 6;
    const int lane = threadIdx.x & 63;
    const int row0 = blockIdx.x * 8 + wave * 2;
    const float4* x0 = (const float4*)(X + (size_t)row0 * DM);
    const float4* x1 = x0 + 128;
    const float4* wd = (const float4*)Wd;
    float4 a0 = x0[2 * lane], a1 = x0[2 * lane + 1];
    float4 b0 = x1[2 * lane], b1 = x1[2 * lane + 1];
    float4 w0 = wd[2 * lane], w1 = wd[2 * lane + 1];
    float s0 = a0.x * w0.x + a0.y * w0.y + a0.z * w0.z + a0.w * w0.w
             + a1.x * w1.x + a1.y * w1.y + a1.z * w1.z + a1.w * w1.w;
    float s1 = b0.x * w0.x + b0.y * w0.y + b0.z * w0.z + b0.w * w0.w
             + b1.x * w1.x + b1.y * w1.y + b1.z * w1.z + b1.w * w1.w;
    half8 h0 = {(half_t)a0.x, (half_t)a0.y, (half_t)a0.z, (half_t)a0.w,
                (half_t)a1.x, (half_t)a1.y, (half_t)a1.z, (half_t)a1.w};
    half8 h1 = {(half_t)b0.x, (half_t)b0.y, (half_t)b0.z, (half_t)b0.w,
                (half_t)b1.x, (half_t)b1.y, (half_t)b1.z, (half_t)b1.w};
    *(half8*)(Xh + (size_t)row0 * DM + lane * 8) = h0;
    *(half8*)(Xh + (size_t)(row0 + 1) * DM + lane * 8) = h1;
#pragma unroll
    for (int off = 32; off > 0; off >>= 1) {
        s0 += __shfl_down(s0, off, 64);
        s1 += __shfl_down(s1, off, 64);
    }
    if (lane == 0) {
        dec[row0]     = 1.0f / (1.0f + __expf(-(s0 + bd[0])));
        dec[row0 + 1] = 1.0f / (1.0f + __expf(-(s1 + bd[0])));
    }
}

// ---------------------------------------------------------------------------
// Wcat_t[768][512] fp16 = [Wi^T ; Wa^T] — 1536 blocks, 1 elem/thread.
// ---------------------------------------------------------------------------
__global__ __launch_bounds__(256) void wcat_transpose(const float* __restrict__ Wi,
                                                      const float* __restrict__ Wa,
                                                      half_t* __restrict__ Wt) {
    const int idx = blockIdx.x * 256 + threadIdx.x;
    const int n = idx >> 9;
    const int k = idx & 511;
    float v = (n < DM) ? Wi[(size_t)k * DM + n] : Wa[(size_t)k * NP + (n - DM)];
    Wt[idx] = (half_t)v;
}

// ---------------------------------------------------------------------------
// Fused MFMA GEMM — single-buffer K-loop + LDS-staged coalesced fp16 epilogue
// (r6: stores are 16B/lane full-line half8 rows; fixes r4's RMW over-fetch).
// ---------------------------------------------------------------------------
__global__ __launch_bounds__(256) void gemm_fused(const half_t* __restrict__ Xh,
                                                  const half_t* __restrict__ Wt,
                                                  const float* __restrict__ bi,
                                                  const float* __restrict__ ba,
                                                  half_t* __restrict__ inj,
                                                  half_t* __restrict__ angles) {
    __shared__ __align__(16) char As[8192];
    __shared__ __align__(16) char Bs[8192];

    const int bm   = blockIdx.x;
    const int bn   = blockIdx.y;
    const int tid  = threadIdx.x;
    const int wave = tid >> 6;
    const int lane = tid & 63;
    const int quad = lane >> 4;
    const int l16  = lane & 15;
    const int wrow = wave >> 1;
    const int wcol = wave & 1;

    floatx4 acc[4][4];
#pragma unroll
    for (int i = 0; i < 4; ++i)
#pragma unroll
        for (int j = 0; j < 4; ++j) acc[i][j] = (floatx4){0.f, 0.f, 0.f, 0.f};

    const int s0 = wave * 128 + lane;
    const int s1 = s0 + 64;
    const int r0 = s0 >> 2, kql0 = (s0 & 3) ^ ((r0 >> 1) & 3);
    const int r1 = s1 >> 2, kql1 = (s1 & 3) ^ ((r1 >> 1) & 3);
    const half_t* gA0 = Xh + (size_t)(bm * 128 + r0) * DM + kql0 * 8;
    const half_t* gA1 = Xh + (size_t)(bm * 128 + r1) * DM + kql1 * 8;
    const half_t* gB0 = Wt + (size_t)(bn * 128 + r0) * DM + kql0 * 8;
    const half_t* gB1 = Wt + (size_t)(bn * 128 + r1) * DM + kql1 * 8;
    char* lA0 = As + wave * 2048;
    char* lA1 = As + wave * 2048 + 1024;
    char* lB0 = Bs + wave * 2048;
    char* lB1 = Bs + wave * 2048 + 1024;

    for (int k0 = 0; k0 < DM; k0 += 32) {
        async_load16(gA0 + k0, lA0);
        async_load16(gA1 + k0, lA1);
        async_load16(gB0 + k0, lB0);
        async_load16(gB1 + k0, lB1);
        __syncthreads();

        half8 af[4], bf[4];
#pragma unroll
        for (int mt = 0; mt < 4; ++mt) {
            const int r = wrow * 64 + mt * 16 + l16;
            af[mt] = *(const half8*)(As + r * 64 + ((quad ^ ((r >> 1) & 3)) << 4));
        }
#pragma unroll
        for (int nt = 0; nt < 4; ++nt) {
            const int r = wcol * 64 + nt * 16 + l16;
            bf[nt] = *(const half8*)(Bs + r * 64 + ((quad ^ ((r >> 1) & 3)) << 4));
        }
#pragma unroll
        for (int mt = 0; mt < 4; ++mt)
#pragma unroll
            for (int nt = 0; nt < 4; ++nt)
                acc[mt][nt] = __builtin_amdgcn_mfma_f32_16x16x32_f16(af[mt], bf[nt],
                                                                     acc[mt][nt], 0, 0, 0);
        __syncthreads();
    }

    // ---- epilogue: LDS-staged coalesced fp16 stores ----
    const bool  is_inj = (bn < 4);
    half_t*     dst    = is_inj ? inj    : angles;
    const int   ldd    = is_inj ? DM     : NP;
    const int   cb     = is_inj ? bn * 128 : bn * 128 - DM;

    float bias[4];
#pragma unroll
    for (int nt = 0; nt < 4; ++nt) {
        const int colt = wcol * 64 + nt * 16 + l16;
        bias[nt] = is_inj ? bi[bn * 128 + colt] : ba[bn * 128 + colt - DM];
    }

    half_t* Cs = (half_t*)As;   // 16 KB = 64 rows x 128 cols fp16
#pragma unroll
    for (int rh = 0; rh < 2; ++rh) {
        __syncthreads();
        if (wrow == rh) {
#pragma unroll
            for (int mt = 0; mt < 4; ++mt)
#pragma unroll
                for (int nt = 0; nt < 4; ++nt)
#pragma unroll
                    for (int r = 0; r < 4; ++r) {
                        const int lr = mt * 16 + quad * 4 + r;
                        const int lc = wcol * 64 + nt * 16 + l16;
                        Cs[lr * 128 + lc] = (half_t)(acc[mt][nt][r] + bias[nt]);
                    }
        }
        __syncthreads();
#pragma unroll
        for (int it = 0; it < 4; ++it) {
            const int idx = it * 256 + tid;      // 0..1023
            const int rr  = idx >> 4;            // 0..63
            const int cc  = (idx & 15) * 8;      // 0..120
            const int grow = bm * 128 + rh * 64 + rr;
            half8 v = *(half8*)(Cs + rr * 128 + cc);
            *(half8*)(dst + (size_t)grow * ldd + cb + cc) = v;
        }
    }
}

// ---------------------------------------------------------------------------
// sum1: per-chunk summaries. CHUNK_LEN=16 -> 1024 blocks.
// ---------------------------------------------------------------------------
__global__ __launch_bounds__(256) void scan_sum1(const half_t* __restrict__ angles,
                                                 const float* __restrict__ decays,
                                                 const half_t* __restrict__ inj,
                                                 float* __restrict__ thetaC,
                                                 float4* __restrict__ hend,
                                                 float* __restrict__ Dprod) {
    const int b   = blockIdx.x >> 7;
    const int sub = threadIdx.x >> 7;
    const int th  = threadIdx.x & 127;
    const int c   = (blockIdx.x & 127) * 2 + sub;
    const int p0  = th * 2;
    const int t0  = c * CHUNK_LEN;

    const half_t* ap = angles + (size_t)(b * SEQ + t0) * NP + p0;
    const half4*  up = (const half4*)(inj + (size_t)(b * SEQ + t0) * DM) + th;
    const float*  dp = decays + b * SEQ + t0;

    half2v ab[2][8]; half4 ub[2][8]; float db[2][8];
#pragma unroll
    for (int j = 0; j < 8; ++j) {
        ab[0][j] = *(const half2v*)(ap + (size_t)j * NP);
        ub[0][j] = up[(size_t)j * 128];
        db[0][j] = dp[j];
    }

    float h0a = 0, h1a = 0, h0b = 0, h1b = 0, tha = 0, thb = 0, dc = 1.0f;
#pragma unroll
    for (int g = 0; g < 2; ++g) {
        const int cur = g & 1, nxt = cur ^ 1;
        if (g < 1) {
#pragma unroll
            for (int j = 0; j < 8; ++j) {
                const int t = (g + 1) * 8 + j;
                ab[nxt][j] = *(const half2v*)(ap + (size_t)t * NP);
                ub[nxt][j] = up[(size_t)t * 128];
                db[nxt][j] = dp[t];
            }
        }
#pragma unroll
        for (int j = 0; j < 8; ++j) {
            float a0 = (float)ab[cur][j][0], a1 = (float)ab[cur][j][1];
            half4 uh = ub[cur][j];
            float d  = db[cur][j];
            float s0, c0, s1, c1;
            __sincosf(a0, &s0, &c0);
            __sincosf(a1, &s1, &c1);
            float n0a = fmaf(d, c0 * h0a - s0 * h1a, (float)uh[0]);
            float n1a = fmaf(d, s0 * h0a + c0 * h1a, (float)uh[1]);
            float n0b = fmaf(d, c1 * h0b - s1 * h1b, (float)uh[2]);
            float n1b = fmaf(d, s1 * h0b + c1 * h1b, (float)uh[3]);
            h0a = n0a; h1a = n1a; h0b = n0b; h1b = n1b;
            tha += a0; thb += a1; dc *= d;
        }
    }
    const size_t cbase = (size_t)(b * CHUNKS + c) * NP + p0;
    *(float2*)(thetaC + cbase) = make_float2(tha, thb);
    hend[cbase >> 1] = make_float4(h0a, h1a, h0b, h1b);
    if (th == 0) Dprod[b * CHUNKS + c] = dc;
}

// ---------------------------------------------------------------------------
// chunk-operator scan — Kogge-Stone in LDS. One block per (b, p-pair).
// ---------------------------------------------------------------------------
__global__ __launch_bounds__(256) void scan_chunks(const float* __restrict__ thetaC,
                                                   const float4* __restrict__ hend,
                                                   const float* __restrict__ Dprod,
                                                   float4* __restrict__ hentry) {
    const int b  = blockIdx.x >> 7;
    const int pp = blockIdx.x & 127;
    const int c  = threadIdx.x;

    __shared__ float  sTa[256], sTb[256], sD[256];
    __shared__ float4 sV[256];

    const size_t idx = (size_t)(b * CHUNKS + c);
    const float2 th2 = *(const float2*)(thetaC + idx * NP + pp * 2);
    float4 v = hend[idx * 128 + pp];
    float  D = Dprod[idx];
    float tha = th2.x, thb = th2.y;

    sTa[c] = tha; sTb[c] = thb; sD[c] = D; sV[c] = v;

#pragma unroll
    for (int o = 1; o < 256; o <<= 1) {
        __syncthreads();
        float lta = 0.f, ltb = 0.f, lD = 0.f;
        float4 lv = make_float4(0.f, 0.f, 0.f, 0.f);
        const bool has = (c >= o);
        if (has) { lta = sTa[c - o]; ltb = sTb[c - o]; lD = sD[c - o]; lv = sV[c - o]; }
        __syncthreads();
        if (has) {
            float s0, c0, s1, c1;
            __sincosf(tha, &s0, &c0);
            __sincosf(thb, &s1, &c1);
            v.x = fmaf(D, c0 * lv.x - s0 * lv.y, v.x);
            v.y = fmaf(D, s0 * lv.x + c0 * lv.y, v.y);
            v.z = fmaf(D, c1 * lv.z - s1 * lv.w, v.z);
            v.w = fmaf(D, s1 * lv.z + c1 * lv.w, v.w);
            tha += lta; thb += ltb; D *= lD;
            sTa[c] = tha; sTb[c] = thb; sD[c] = D; sV[c] = v;
        }
    }
    __syncthreads();
    const float4 e = (c == 0) ? make_float4(0.f, 0.f, 0.f, 0.f) : sV[c - 1];
    hentry[idx * 128 + pp] = e;
}

// ---------------------------------------------------------------------------
// final: redo local scan seeded with entry state; inj fp16; write out fp32.
// ---------------------------------------------------------------------------
__global__ __launch_bounds__(256) void scan_final(const half_t* __restrict__ angles,
                                                  const float* __restrict__ decays,
                                                  const half_t* __restrict__ inj,
                                                  const float4* __restrict__ hentry,
                                                  float* __restrict__ out) {
    const int b   = blockIdx.x >> 7;
    const int sub = threadIdx.x >> 7;
    const int th  = threadIdx.x & 127;
    const int c   = (blockIdx.x & 127) * 2 + sub;
    const int p0  = th * 2;
    const int t0  = c * CHUNK_LEN;

    const half_t* ap = angles + (size_t)(b * SEQ + t0) * NP + p0;
    const half4*  up = (const half4*)(inj + (size_t)(b * SEQ + t0) * DM) + th;
    float4*       op = (float4*)out + (size_t)(b * SEQ + t0) * 128 + (p0 >> 1);
    const float*  dp = decays + b * SEQ + t0;

    float4 v = hentry[(size_t)(b * CHUNKS + c) * 128 + (p0 >> 1)];
    float h0a = v.x, h1a = v.y, h0b = v.z, h1b = v.w;

    half2v ab[2][8]; half4 ub[2][8]; float db[2][8];
#pragma unroll
    for (int j = 0; j < 8; ++j) {
        ab[0][j] = *(const half2v*)(ap + (size_t)j * NP);
        ub[0][j] = up[(size_t)j * 128];
        db[0][j] = dp[j];
    }

#pragma unroll
    for (int g = 0; g < 2; ++g) {
        const int cur = g & 1, nxt = cur ^ 1;
        if (g < 1) {
#pragma unroll
            for (int j = 0; j < 8; ++j) {
                const int t = (g + 1) * 8 + j;
                ab[nxt][j] = *(const half2v*)(ap + (size_t)t * NP);
                ub[nxt][j] = up[(size_t)t * 128];
                db[nxt][j] = dp[t];
            }
        }
#pragma unroll
        for (int j = 0; j < 8; ++j) {
            const int t = g * 8 + j;
            float a0 = (float)ab[cur][j][0], a1 = (float)ab[cur][j][1];
            half4 uh = ub[cur][j];
            float d  = db[cur][j];
            float s0, c0, s1, c1;
            __sincosf(a0, &s0, &c0);
            __sincosf(a1, &s1, &c1);
            float n0a = fmaf(d, c0 * h0a - s0 * h1a, (float)uh[0]);
            float n1a = fmaf(d, s0 * h0a + c0 * h1a, (float)uh[1]);
            float n0b = fmaf(d, c1 * h0b - s1 * h1b, (float)uh[2]);
            float n1b = fmaf(d, s1 * h0b + c1 * h1b, (float)uh[3]);
            h0a = n0a; h1a = n1a; h0b = n0b; h1b = n1b;
            op[(size_t)t * 128] = make_float4(h0a, h1a, h0b, h1b);
        }
    }
}

// ---------------------------------------------------------------------------
extern "C" void kernel_launch(void* const* d_in, const int* in_sizes, int n_in,
                              void* d_out, int out_size, void* d_ws, size_t ws_size,
                              hipStream_t stream) {
    const float* x  = (const float*)d_in[0];
    const float* Wa = (const float*)d_in[1];
    const float* ba = (const float*)d_in[2];
    const float* Wd = (const float*)d_in[3];
    const float* bd = (const float*)d_in[4];
    const float* Wi = (const float*)d_in[5];
    const float* bi = (const float*)d_in[6];
    float* out = (float*)d_out;

    char* ws = (char*)d_ws;
    half_t* x_h     = (half_t*)(ws);                  // 33,554,432 B @ 0 (dead after gemm)
    float*  thetaC  = (float*)(ws);                   //  2,097,152 B (overlay, post-gemm)
    float4* hend    = (float4*)(ws + 2097152);        //  4,194,304 B (overlay)
    float*  Dprod   = (float*)(ws + 6291456);         //      8,192 B (overlay)
    float4* hentry  = (float4*)(ws + 6299648);        //  4,194,304 B (overlay)
    half_t* inj_h   = (half_t*)(ws + 33554432);       // 33,554,432 B
    half_t* angles  = (half_t*)(ws + 67108864);       // 16,777,216 B
    float*  decays  = (float*)(ws + 83886080);        //    131,072 B
    half_t* Wcat_t  = (half_t*)(ws + 84017152);       //    786,432 B  (ends 84,803,584)

    decay_convert<<<M_TOT / 8, 256, 0, stream>>>(x, Wd, bd, decays, x_h);
    wcat_transpose<<<(NTOT * DM) / 256, 256, 0, stream>>>(Wi, Wa, Wcat_t);
    gemm_fused<<<dim3(M_TOT / 128, NTOT / 128), 256, 0, stream>>>(x_h, Wcat_t, bi, ba, inj_h, angles);

    scan_sum1<<<BATCH * CHUNKS / 2, 256, 0, stream>>>(angles, decays, inj_h, thetaC, hend, Dprod);
    scan_chunks<<<BATCH * 128, 256, 0, stream>>>(thetaC, hend, Dprod, hentry);
    scan_final<<<BATCH * CHUNKS / 2, 256, 0, stream>>>(angles, decays, inj_h, hentry, out);
}